// Round 2
// baseline (1571.218 us; speedup 1.0000x reference)
//
#include <hip/hip_runtime.h>
#include <hip/hip_bf16.h>

// ---------------------------------------------------------------------------
// Fused 3-layer GRU (Keras reset_after) + dense + softmax for MI355X (gfx950).
// B=131072, T=3, F=223, units (128,64,32), 17 classes.
// Strategy: fp16 MFMA (16x16x32) with fp32 accumulation; weights pre-converted
// to f16 transposed [N][K] in d_ws so B-fragments are contiguous 16B loads.
// Per block: 32 batch rows; x staged in LDS per timestep; h kept in fp32 regs
// (exact GRU update) and mirrored f16 in LDS as A-operand for next GEMMs.
// ---------------------------------------------------------------------------

typedef _Float16 half8 __attribute__((ext_vector_type(8)));
typedef float f32x4 __attribute__((ext_vector_type(4)));

#define MFMA16(a, b, c) __builtin_amdgcn_mfma_f32_16x16x32_f16((a), (b), (c), 0, 0, 0)

// d_ws layout (f16 elements):
//   k1T  [384][224] @ 0        (86016)   (K padded 223->224, pad = 0)
//   rk1T [384][128] @ 86016    (49152)
//   k2T  [192][128] @ 135168   (24576)
//   rk2T [192][ 64] @ 159744   (12288)
//   k3T  [ 96][ 64] @ 172032   ( 6144)
//   rk3T [ 96][ 32] @ 178176   ( 3072)   total 181248 elems = 362496 B
#define OFF_RK1 86016
#define OFF_K2  135168
#define OFF_RK2 159744
#define OFF_K3  172032
#define OFF_RK3 178176
#define WS_ELEMS 181248

__global__ void prep_weights(const float* __restrict__ k1, const float* __restrict__ rk1,
                             const float* __restrict__ k2, const float* __restrict__ rk2,
                             const float* __restrict__ k3, const float* __restrict__ rk3,
                             _Float16* __restrict__ o) {
    int i = blockIdx.x * 256 + threadIdx.x;
    if (i < 86016) {                    // k1T [384][224] <- k1 [223][384]
        int n = i / 224, k = i - n * 224;
        o[i] = (_Float16)(k < 223 ? k1[k * 384 + n] : 0.0f);
        return;
    }
    i -= 86016;
    if (i < 49152) {                    // rk1T [384][128] <- rk1 [128][384]
        int n = i / 128, k = i - n * 128;
        o[OFF_RK1 + i] = (_Float16)rk1[k * 384 + n];
        return;
    }
    i -= 49152;
    if (i < 24576) {                    // k2T [192][128] <- k2 [128][192]
        int n = i / 128, k = i - n * 128;
        o[OFF_K2 + i] = (_Float16)k2[k * 192 + n];
        return;
    }
    i -= 24576;
    if (i < 12288) {                    // rk2T [192][64] <- rk2 [64][192]
        int n = i / 64, k = i - n * 64;
        o[OFF_RK2 + i] = (_Float16)rk2[k * 192 + n];
        return;
    }
    i -= 12288;
    if (i < 6144) {                     // k3T [96][64] <- k3 [64][96]
        int n = i / 64, k = i - n * 64;
        o[OFF_K3 + i] = (_Float16)k3[k * 96 + n];
        return;
    }
    i -= 6144;
    if (i < 3072) {                     // rk3T [96][32] <- rk3 [32][96]
        int n = i / 32, k = i - n * 32;
        o[OFF_RK3 + i] = (_Float16)rk3[k * 96 + n];
        return;
    }
}

__device__ __forceinline__ float sigmoidf_(float v) { return 1.0f / (1.0f + __expf(-v)); }
__device__ __forceinline__ float tanhf_(float v) { return 1.0f - 2.0f / (1.0f + __expf(2.0f * v)); }

// LDS strides (in f16 elems), chosen 16B-aligned with bank spread.
#define XS_STR  232   // x tile: 32 x 232 (cols 0..223 valid, 223 zero-padded)
#define H1_STR  136   // h1: 32 x 136 (cols 0..127)
#define H2_STR  72    // h2: 32 x 72  (cols 0..63)
#define H3_STR  40    // h3: 32 x 40  (cols 0..31)

__global__ __launch_bounds__(256, 2) void gru_fused(
    const float* __restrict__ x, const _Float16* __restrict__ wts,
    const float* __restrict__ b1, const float* __restrict__ b2, const float* __restrict__ b3,
    const float* __restrict__ Wd, const float* __restrict__ bd,
    float* __restrict__ out) {
    __shared__ _Float16 smem[32 * XS_STR + 32 * H1_STR + 32 * H2_STR + 32 * H3_STR];
    _Float16* xs  = smem;
    _Float16* hs1 = smem + 32 * XS_STR;
    _Float16* hs2 = hs1 + 32 * H1_STR;
    _Float16* hs3 = hs2 + 32 * H2_STR;

    const int tid  = threadIdx.x;
    const int lane = tid & 63;
    const int w    = tid >> 6;          // wave 0..3
    const int ln15 = lane & 15;
    const int kg8  = (lane >> 4) * 8;   // k-offset of this lane's 8-elem block
    const int rowg = (lane >> 4) * 4;   // C/D row group
    const int b0   = blockIdx.x * 32;

    const _Float16* k1T  = wts;
    const _Float16* rk1T = wts + OFF_RK1;
    const _Float16* k2T  = wts + OFF_K2;
    const _Float16* rk2T = wts + OFF_RK2;
    const _Float16* k3T  = wts + OFF_K3;
    const _Float16* rk3T = wts + OFF_RK3;

    // zero h LDS (h1,h2,h3 contiguous): 32*(136+72+40) = 7936 halves = 3968 u32
    for (int i = tid; i < 3968; i += 256) ((unsigned*)hs1)[i] = 0u;

    // --- per-thread biases ---
    const int u1b = w * 32;             // L1: wave owns units [32w, 32w+32)
    float bi1[3][2], br1[3][2], bi2[3], br2[3], bi3[3], br3[3];
#pragma unroll
    for (int s = 0; s < 3; ++s)
#pragma unroll
        for (int ci = 0; ci < 2; ++ci) {
            int u = u1b + ci * 16 + ln15;
            bi1[s][ci] = b1[s * 128 + u];
            br1[s][ci] = b1[384 + s * 128 + u];
        }
    {
        int u2 = w * 16 + ln15;         // L2: wave owns units [16w, 16w+16)
#pragma unroll
        for (int s = 0; s < 3; ++s) { bi2[s] = b2[s * 64 + u2]; br2[s] = b2[192 + s * 64 + u2]; }
        int u3 = (w & 1) * 16 + ln15;   // L3: waves (0,1)/(2,3) -> units, rows split
#pragma unroll
        for (int s = 0; s < 3; ++s) { bi3[s] = b3[s * 32 + u3]; br3[s] = b3[96 + s * 32 + u3]; }
    }
    const int mi3 = w >> 1;

    float h1r[2][2][4]; // [ci][mi][r]
    float h2r[2][4];    // [mi][r]
    float h3r[4];
#pragma unroll
    for (int ci = 0; ci < 2; ++ci)
#pragma unroll
        for (int mi = 0; mi < 2; ++mi)
#pragma unroll
            for (int r = 0; r < 4; ++r) h1r[ci][mi][r] = 0.0f;
#pragma unroll
    for (int mi = 0; mi < 2; ++mi)
#pragma unroll
        for (int r = 0; r < 4; ++r) h2r[mi][r] = 0.0f;
#pragma unroll
    for (int r = 0; r < 4; ++r) h3r[r] = 0.0f;

    const f32x4 z4 = {0.0f, 0.0f, 0.0f, 0.0f};
    __syncthreads();

    for (int t = 0; t < 3; ++t) {
        // ---- stage x_t tile -> LDS f16 (rows = batch, 223 cols + zero pad) ----
        for (int p = tid; p < 32 * 112; p += 256) {
            int m = p / 112, q = p - m * 112;
            const float* xr = x + ((size_t)(b0 + m) * 3 + t) * 223;
            float v0 = xr[2 * q];
            float v1 = (2 * q + 1 < 223) ? xr[2 * q + 1] : 0.0f;
            union { _Float16 h[2]; unsigned u; } pk;
            pk.h[0] = (_Float16)v0;
            pk.h[1] = (_Float16)v1;
            *(unsigned*)&xs[m * XS_STR + 2 * q] = pk.u;
        }
        __syncthreads();

        // ================= Layer 1 (K=224 in, K=128 rec, N=384) =================
        f32x4 aX[3][2][2], aI[3][2][2]; // [sec][ci][mi]
#pragma unroll
        for (int s = 0; s < 3; ++s)
#pragma unroll
            for (int ci = 0; ci < 2; ++ci)
#pragma unroll
                for (int mi = 0; mi < 2; ++mi) { aX[s][ci][mi] = z4; aI[s][ci][mi] = z4; }

#pragma unroll
        for (int ks = 0; ks < 7; ++ks) {
            int k0 = ks * 32;
            half8 a0 = *(const half8*)(xs + ln15 * XS_STR + k0 + kg8);
            half8 a1 = *(const half8*)(xs + (16 + ln15) * XS_STR + k0 + kg8);
#pragma unroll
            for (int s = 0; s < 3; ++s)
#pragma unroll
                for (int ci = 0; ci < 2; ++ci) {
                    int n0 = s * 128 + u1b + ci * 16;
                    half8 bf = *(const half8*)(k1T + (size_t)(n0 + ln15) * 224 + k0 + kg8);
                    aX[s][ci][0] = MFMA16(a0, bf, aX[s][ci][0]);
                    aX[s][ci][1] = MFMA16(a1, bf, aX[s][ci][1]);
                }
        }
#pragma unroll
        for (int ks = 0; ks < 4; ++ks) {
            int k0 = ks * 32;
            half8 a0 = *(const half8*)(hs1 + ln15 * H1_STR + k0 + kg8);
            half8 a1 = *(const half8*)(hs1 + (16 + ln15) * H1_STR + k0 + kg8);
#pragma unroll
            for (int s = 0; s < 3; ++s)
#pragma unroll
                for (int ci = 0; ci < 2; ++ci) {
                    int n0 = s * 128 + u1b + ci * 16;
                    half8 bf = *(const half8*)(rk1T + (size_t)(n0 + ln15) * 128 + k0 + kg8);
                    aI[s][ci][0] = MFMA16(a0, bf, aI[s][ci][0]);
                    aI[s][ci][1] = MFMA16(a1, bf, aI[s][ci][1]);
                }
        }
        __syncthreads(); // all waves done reading hs1 (t-1) and xs
#pragma unroll
        for (int ci = 0; ci < 2; ++ci)
#pragma unroll
            for (int mi = 0; mi < 2; ++mi)
#pragma unroll
                for (int r = 0; r < 4; ++r) {
                    float xz = aX[0][ci][mi][r] + bi1[0][ci];
                    float iz = aI[0][ci][mi][r] + br1[0][ci];
                    float xr_ = aX[1][ci][mi][r] + bi1[1][ci];
                    float ir = aI[1][ci][mi][r] + br1[1][ci];
                    float xh = aX[2][ci][mi][r] + bi1[2][ci];
                    float ih = aI[2][ci][mi][r] + br1[2][ci];
                    float zg = sigmoidf_(xz + iz);
                    float rg = sigmoidf_(xr_ + ir);
                    float hh = tanhf_(xh + rg * ih);
                    float hn = zg * h1r[ci][mi][r] + (1.0f - zg) * hh;
                    h1r[ci][mi][r] = hn;
                    int m = mi * 16 + rowg + r;
                    hs1[m * H1_STR + u1b + ci * 16 + ln15] = (_Float16)hn;
                }
        __syncthreads(); // hs1 = h1_t ready

        // ================= Layer 2 (K=128 in, K=64 rec, N=192) =================
        f32x4 aX2[3][2], aI2[3][2];
#pragma unroll
        for (int s = 0; s < 3; ++s)
#pragma unroll
            for (int mi = 0; mi < 2; ++mi) { aX2[s][mi] = z4; aI2[s][mi] = z4; }
#pragma unroll
        for (int ks = 0; ks < 4; ++ks) {
            int k0 = ks * 32;
            half8 a0 = *(const half8*)(hs1 + ln15 * H1_STR + k0 + kg8);
            half8 a1 = *(const half8*)(hs1 + (16 + ln15) * H1_STR + k0 + kg8);
#pragma unroll
            for (int s = 0; s < 3; ++s) {
                int n0 = s * 64 + w * 16;
                half8 bf = *(const half8*)(k2T + (size_t)(n0 + ln15) * 128 + k0 + kg8);
                aX2[s][0] = MFMA16(a0, bf, aX2[s][0]);
                aX2[s][1] = MFMA16(a1, bf, aX2[s][1]);
            }
        }
#pragma unroll
        for (int ks = 0; ks < 2; ++ks) {
            int k0 = ks * 32;
            half8 a0 = *(const half8*)(hs2 + ln15 * H2_STR + k0 + kg8);
            half8 a1 = *(const half8*)(hs2 + (16 + ln15) * H2_STR + k0 + kg8);
#pragma unroll
            for (int s = 0; s < 3; ++s) {
                int n0 = s * 64 + w * 16;
                half8 bf = *(const half8*)(rk2T + (size_t)(n0 + ln15) * 64 + k0 + kg8);
                aI2[s][0] = MFMA16(a0, bf, aI2[s][0]);
                aI2[s][1] = MFMA16(a1, bf, aI2[s][1]);
            }
        }
        __syncthreads(); // done reading hs1(t), hs2(t-1)
#pragma unroll
        for (int mi = 0; mi < 2; ++mi)
#pragma unroll
            for (int r = 0; r < 4; ++r) {
                float xz = aX2[0][mi][r] + bi2[0];
                float iz = aI2[0][mi][r] + br2[0];
                float xr_ = aX2[1][mi][r] + bi2[1];
                float ir = aI2[1][mi][r] + br2[1];
                float xh = aX2[2][mi][r] + bi2[2];
                float ih = aI2[2][mi][r] + br2[2];
                float zg = sigmoidf_(xz + iz);
                float rg = sigmoidf_(xr_ + ir);
                float hh = tanhf_(xh + rg * ih);
                float hn = zg * h2r[mi][r] + (1.0f - zg) * hh;
                h2r[mi][r] = hn;
                int m = mi * 16 + rowg + r;
                hs2[m * H2_STR + w * 16 + ln15] = (_Float16)hn;
            }
        __syncthreads(); // hs2 = h2_t ready

        // ================= Layer 3 (K=64 in, K=32 rec, N=96) =================
        // wave w: rows [16*(w>>1), +16), units [16*(w&1), +16)
        f32x4 aX3[3], aI3[3];
#pragma unroll
        for (int s = 0; s < 3; ++s) { aX3[s] = z4; aI3[s] = z4; }
#pragma unroll
        for (int ks = 0; ks < 2; ++ks) {
            int k0 = ks * 32;
            half8 a = *(const half8*)(hs2 + (mi3 * 16 + ln15) * H2_STR + k0 + kg8);
#pragma unroll
            for (int s = 0; s < 3; ++s) {
                int n0 = s * 32 + (w & 1) * 16;
                half8 bf = *(const half8*)(k3T + (size_t)(n0 + ln15) * 64 + k0 + kg8);
                aX3[s] = MFMA16(a, bf, aX3[s]);
            }
        }
        {
            half8 a = *(const half8*)(hs3 + (mi3 * 16 + ln15) * H3_STR + kg8);
#pragma unroll
            for (int s = 0; s < 3; ++s) {
                int n0 = s * 32 + (w & 1) * 16;
                half8 bf = *(const half8*)(rk3T + (size_t)(n0 + ln15) * 32 + kg8);
                aI3[s] = MFMA16(a, bf, aI3[s]);
            }
        }
        __syncthreads(); // done reading hs2(t), hs3(t-1)
#pragma unroll
        for (int r = 0; r < 4; ++r) {
            float xz = aX3[0][r] + bi3[0];
            float iz = aI3[0][r] + br3[0];
            float xr_ = aX3[1][r] + bi3[1];
            float ir = aI3[1][r] + br3[1];
            float xh = aX3[2][r] + bi3[2];
            float ih = aI3[2][r] + br3[2];
            float zg = sigmoidf_(xz + iz);
            float rg = sigmoidf_(xr_ + ir);
            float hh = tanhf_(xh + rg * ih);
            float hn = zg * h3r[r] + (1.0f - zg) * hh;
            h3r[r] = hn;
            int m = mi3 * 16 + rowg + r;
            hs3[m * H3_STR + (w & 1) * 16 + ln15] = (_Float16)hn;
        }
        __syncthreads(); // hs3 = h3_t ready
    } // t

    // ================= Dense (32 -> 17) + softmax =================
    float* lg = (float*)xs; // reuse x LDS: 32 rows x stride 20 floats
    for (int idx = tid; idx < 32 * 17; idx += 256) {
        int m = idx / 17, c = idx - m * 17;
        float acc = bd[c];
#pragma unroll
        for (int k = 0; k < 32; ++k) acc += (float)hs3[m * H3_STR + k] * Wd[k * 17 + c];
        lg[m * 20 + c] = acc;
    }
    __syncthreads();
    if (tid < 32) {
        int m = tid;
        float mx = -1e30f;
#pragma unroll
        for (int c = 0; c < 17; ++c) mx = fmaxf(mx, lg[m * 20 + c]);
        float sum = 0.0f;
#pragma unroll
        for (int c = 0; c < 17; ++c) sum += __expf(lg[m * 20 + c] - mx);
        float inv = 1.0f / sum;
        float* op = out + (size_t)(b0 + m) * 17;
#pragma unroll
        for (int c = 0; c < 17; ++c) op[c] = __expf(lg[m * 20 + c] - mx) * inv;
    }
}

extern "C" void kernel_launch(void* const* d_in, const int* in_sizes, int n_in,
                              void* d_out, int out_size, void* d_ws, size_t ws_size,
                              hipStream_t stream) {
    const float* x   = (const float*)d_in[0];
    const float* k1  = (const float*)d_in[1];
    const float* rk1 = (const float*)d_in[2];
    const float* b1  = (const float*)d_in[3];
    const float* k2  = (const float*)d_in[4];
    const float* rk2 = (const float*)d_in[5];
    const float* b2  = (const float*)d_in[6];
    const float* k3  = (const float*)d_in[7];
    const float* rk3 = (const float*)d_in[8];
    const float* b3  = (const float*)d_in[9];
    const float* Wd  = (const float*)d_in[10];
    const float* bd  = (const float*)d_in[11];
    float* out = (float*)d_out;
    _Float16* wts = (_Float16*)d_ws;

    // weights -> f16 transposed in d_ws (same work every call; ws re-poisoned)
    prep_weights<<<dim3(WS_ELEMS / 256), dim3(256), 0, stream>>>(k1, rk1, k2, rk2, k3, rk3, wts);

    // fused GRU stack: 131072/32 = 4096 blocks of 256 threads
    gru_fused<<<dim3(4096), dim3(256), 0, stream>>>(x, wts, b1, b2, b3, Wd, bd, out);
}